// Round 8
// baseline (299.295 us; speedup 1.0000x reference)
//
#include <hip/hip_runtime.h>
#include <cstdint>
#include <cstddef>

typedef __bf16 bf16x8 __attribute__((ext_vector_type(8)));
typedef __bf16 bf16x4 __attribute__((ext_vector_type(4)));
typedef float f32x4 __attribute__((ext_vector_type(4)));

__device__ __forceinline__ void gload16(const void* g, void* l) {
  __builtin_amdgcn_global_load_lds((const __attribute__((address_space(1))) void*)g,
                                   (__attribute__((address_space(3))) void*)l, 16, 0, 0);
}

__device__ __forceinline__ float exp2_fast(float x) {
  float r;
  asm("v_exp_f32 %0, %1" : "=v"(r) : "v"(x));
  return r;
}
__device__ __forceinline__ float rcp_fast(float x) {
  float r;
  asm("v_rcp_f32 %0, %1" : "=v"(r) : "v"(x));
  return r;
}

template<int N> __device__ __forceinline__ void wait_vm() {
  if constexpr (N == 0) asm volatile("s_waitcnt vmcnt(0)" ::: "memory");
  else if constexpr (N == 2) asm volatile("s_waitcnt vmcnt(2)" ::: "memory");
  else if constexpr (N == 3) asm volatile("s_waitcnt vmcnt(3)" ::: "memory");
  else if constexpr (N == 4) asm volatile("s_waitcnt vmcnt(4)" ::: "memory");
  else if constexpr (N == 6) asm volatile("s_waitcnt vmcnt(6)" ::: "memory");
  else if constexpr (N == 8) asm volatile("s_waitcnt vmcnt(8)" ::: "memory");
}

#define S_BARRIER() __builtin_amdgcn_s_barrier()
#define WAIT_VM4()  asm volatile("s_waitcnt vmcnt(4)" ::: "memory")
#define WAIT_VM0()  asm volatile("s_waitcnt vmcnt(0)" ::: "memory")
#define WAIT_LGKM() asm volatile("s_waitcnt lgkmcnt(0)" ::: "memory")

// ---------------- LayerNorm: fp32 in -> bf16 out (row = 768) ----------------
__global__ __launch_bounds__(256) void ln_kernel(const float* __restrict__ x,
    const float* __restrict__ g, const float* __restrict__ b,
    __bf16* __restrict__ out)
{
  __shared__ float red[8];
  const int row = blockIdx.x, t = threadIdx.x;
  const float* xr = x + (size_t)row * 768;
  float v0 = xr[t], v1 = xr[t + 256], v2 = xr[t + 512];
  float s = v0 + v1 + v2;
  float q = v0 * v0 + v1 * v1 + v2 * v2;
  #pragma unroll
  for (int off = 32; off > 0; off >>= 1) {
    s += __shfl_xor(s, off, 64);
    q += __shfl_xor(q, off, 64);
  }
  const int w = t >> 6;
  if ((t & 63) == 0) { red[w] = s; red[4 + w] = q; }
  __syncthreads();
  s = red[0] + red[1] + red[2] + red[3];
  q = red[4] + red[5] + red[6] + red[7];
  const float mu = s * (1.0f / 768.0f);
  const float var = q * (1.0f / 768.0f) - mu * mu;
  const float rstd = rsqrtf(var + 1e-5f);
  __bf16* orow = out + (size_t)row * 768;
  orow[t]       = (__bf16)((v0 - mu) * rstd * g[t]       + b[t]);
  orow[t + 256] = (__bf16)((v1 - mu) * rstd * g[t + 256] + b[t + 256]);
  orow[t + 512] = (__bf16)((v2 - mu) * rstd * g[t + 512] + b[t + 512]);
}

// ---------------- fused fp32 -> bf16 cast of all 4 weight matrices ----------------
__global__ __launch_bounds__(256) void cast4_kernel(
    const float* __restrict__ i0, const float* __restrict__ i1,
    const float* __restrict__ i2, const float* __restrict__ i3,
    __bf16* __restrict__ o0, __bf16* __restrict__ o1,
    __bf16* __restrict__ o2, __bf16* __restrict__ o3)
{
  const int n0 = 2304 * 768 / 4, n1 = 768 * 768 / 4;
  const int n2 = 3072 * 768 / 4, n3 = 768 * 3072 / 4;
  const int total = n0 + n1 + n2 + n3;
  for (int i = blockIdx.x * 256 + threadIdx.x; i < total; i += gridDim.x * 256) {
    const float* in; __bf16* out; int j = i;
    if (j < n0) { in = i0; out = o0; }
    else if ((j -= n0) < n1) { in = i1; out = o1; }
    else if ((j -= n1) < n2) { in = i2; out = o2; }
    else { j -= n2; in = i3; out = o3; }
    float4 v = ((const float4*)in)[j];
    bf16x4 o = { (__bf16)v.x, (__bf16)v.y, (__bf16)v.z, (__bf16)v.w };
    ((bf16x4*)out)[j] = o;
  }
}

// ---------------- GEMM v6: C[M,N] = A[M,K](bf16) @ W[N,K]^T(bf16) ----------------
// BMxBN tile (128x128 or 64x64), BK=32, 4 waves (2x2), 16x16x32 bf16 MFMA.
// NBUF=2, depth-1 counted prefetch (attn-kernel-proven pattern), small LDS to
// maximize resident blocks/CU (m102: blocks/CU is the dominant perf variable).
//   128x128: LDS 32 KB -> up to 5 blocks/CU.  64x64: LDS 16 KB -> 6+ blocks/CU.
// LDS granule XOR-swizzle (pre-swizzled source + swizzled read) -> 0 bank conflicts.
// XCD-aware bijective block swizzle (grids all %8==0).
// MODE 0: QKV scatter (Q scaled 0.125*log2e, V transposed). MODE 1: proj (+bias, resid+ls).
// MODE 2: fc1 (+bias, fast GELU -> bf16). MODE 3: fc2 (+bias, resid+ls -> f32).
template<int MODE, int BM, int BN>
__global__ __launch_bounds__(256) void gemm_kernel(
    const __bf16* __restrict__ A, const __bf16* __restrict__ W, int K,
    const float* __restrict__ bias, const float* __restrict__ resid,
    const float* __restrict__ ls, float* __restrict__ outf,
    __bf16* __restrict__ outb,
    __bf16* __restrict__ qo, __bf16* __restrict__ ko, __bf16* __restrict__ vo)
{
  constexpr int FM = BM / 32;          // m-fragments per wave (4 or 2)
  constexpr int FN = BN / 32;          // n-fragments per wave (4 or 2)
  constexpr int WMS = BM / 2;          // per-wave m-span
  constexpr int WNS = BN / 2;          // per-wave n-span
  constexpr int ASTRIDE = BM * 32;     // elements per A buffer
  constexpr int BSTRIDE = BN * 32;     // elements per B buffer
  constexpr int LPT = BM / 64 + BN / 64;  // global_load_lds per tile (4 or 2)
  __shared__ __bf16 As[2 * ASTRIDE];
  __shared__ __bf16 Bs[2 * BSTRIDE];

  // XCD-aware swizzle of the linear block id (bijective: nwg % 8 == 0)
  const int nx = gridDim.x;
  const int nwg = nx * gridDim.y;
  const int orig = blockIdx.x + nx * blockIdx.y;
  const int nid = (orig & 7) * (nwg >> 3) + (orig >> 3);
  const int bx = nid % nx, by = nid / nx;

  const int t = threadIdx.x;
  const int lane = t & 63;
  const int w = t >> 6;
  const int wm = w >> 1, wn = w & 1;
  const int m0 = by * BM, n0 = bx * BN;
  const int rl = lane & 15, gs = lane >> 4;

  f32x4 acc[FM][FN];
  #pragma unroll
  for (int i = 0; i < FM; ++i)
    #pragma unroll
    for (int j = 0; j < FN; ++j) acc[i][j] = { 0.f, 0.f, 0.f, 0.f };

  const int ra = t >> 2;                              // staging row 0..63
  const int ca = (((t & 3) ^ ((ra >> 1) & 3))) * 8;   // pre-swizzled source granule
  const __bf16* Ag = A + (size_t)(m0 + ra) * K + ca;
  const __bf16* Wg = W + (size_t)(n0 + ra) * K + ca;
  const size_t rowskip = (size_t)64 * K;

  auto stage = [&](int kt, int buf) {
    const int k0 = kt << 5;
    __bf16* da = As + buf * ASTRIDE + t * 8;
    __bf16* db = Bs + buf * BSTRIDE + t * 8;
    gload16(Ag + k0, da);
    if constexpr (BM == 128) gload16(Ag + rowskip + k0, da + 2048);
    gload16(Wg + k0, db);
    if constexpr (BN == 128) gload16(Wg + rowskip + k0, db + 2048);
  };

  const int nk = K >> 5;          // 24 or 96
  stage(0, 0);

  #pragma unroll 2
  for (int kt = 0; kt < nk; ++kt) {
    const int cur = kt & 1;
    if (kt + 1 < nk) { stage(kt + 1, cur ^ 1); wait_vm<LPT>(); }
    else             { wait_vm<0>(); }
    S_BARRIER();                  // tile kt resident for all waves

    const __bf16* Ac = As + cur * ASTRIDE;
    const __bf16* Bc = Bs + cur * BSTRIDE;
    bf16x8 af[FM], bfr[FN];
    #pragma unroll
    for (int fm = 0; fm < FM; ++fm) {
      const int row = wm * WMS + fm * 16 + rl;
      af[fm] = *(const bf16x8*)(Ac + row * 32 + (gs ^ ((row >> 1) & 3)) * 8);
    }
    #pragma unroll
    for (int fn = 0; fn < FN; ++fn) {
      const int row = wn * WNS + fn * 16 + rl;
      bfr[fn] = *(const bf16x8*)(Bc + row * 32 + (gs ^ ((row >> 1) & 3)) * 8);
    }
    #pragma unroll
    for (int fm = 0; fm < FM; ++fm)
      #pragma unroll
      for (int fn = 0; fn < FN; ++fn)
        acc[fm][fn] = __builtin_amdgcn_mfma_f32_16x16x32_bf16(af[fm], bfr[fn], acc[fm][fn], 0, 0, 0);

    S_BARRIER();                  // all waves done with tile kt before its buffer is re-staged
  }

  // epilogue: C row = m0+wm*WMS+fm*16+gs*4+b ; col = n0+wn*WNS+fn*16+rl
  #pragma unroll
  for (int fm = 0; fm < FM; ++fm) {
    const int rbase = m0 + wm * WMS + fm * 16 + gs * 4;
    #pragma unroll
    for (int fn = 0; fn < FN; ++fn) {
      const int c = n0 + wn * WNS + fn * 16 + rl;
      #pragma unroll
      for (int b = 0; b < 4; ++b) {
        const int r = rbase + b;
        const float val = acc[fm][fn][b];
        if constexpr (MODE == 0) {
          const int sec = c / 768;
          const int cc = c - sec * 768;
          const int hh = cc >> 6, d = cc & 63;
          const int batch = r >> 10, n = r & 1023;
          const size_t bh = (size_t)(batch * 12 + hh);
          // Q scaled by (1/8)*log2(e) so softmax uses raw v_exp_f32 (2^x)
          if (sec == 0)      qo[(bh * 1024 + n) * 64 + d] = (__bf16)(val * 0.1803368801111204f);
          else if (sec == 1) ko[(bh * 1024 + n) * 64 + d] = (__bf16)val;
          else               vo[(bh * 64 + d) * 1024 + n] = (__bf16)val;
        } else if constexpr (MODE == 1) {
          const size_t idx = (size_t)r * 768 + c;
          outf[idx] = resid[idx] + ls[c] * (val + bias[c]);
        } else if constexpr (MODE == 2) {
          // fast GELU: h*sigmoid(2*0.7978845608*(h+0.044715 h^3)), exp2-folded.
          const float h = val + bias[c];
          const float z = h * (1.0f + 0.044715f * h * h);
          const float e = exp2_fast(2.3021181f * z);   // 2*0.79788456*log2(e) * z
          const float gl = h - h * rcp_fast(1.0f + e);
          outb[(size_t)r * 3072 + c] = (__bf16)gl;
        } else {
          const size_t idx = (size_t)r * 768 + c;
          outf[idx] = resid[idx] + ls[c] * (val + bias[c]);
        }
      }
    }
  }
}

// ---------------- Flash attention (fixed-max exp2 softmax, deferred denom) ----
// Q: [96][1024][64] bf16 pre-scaled by 0.125*log2e. K: [96][1024][64]. Vt: [96][64][1024].
// Block-id mapping puts all 8 q-tiles of a head on one XCD (12 heads x 256KB = 3MB < 4MB L2).
__global__ __launch_bounds__(256, 3) void attn_kernel(
    const __bf16* __restrict__ Q, const __bf16* __restrict__ Kb,
    const __bf16* __restrict__ Vt, __bf16* __restrict__ Ob)
{
  __shared__ __bf16 Ks[2][64 * 64];     // 2 x 8 KB
  __shared__ __bf16 Vs[2][64 * 64];     // 2 x 8 KB
  __shared__ __bf16 P_lds[4][32 * 72];  // per-wave P, rows padded to 72 halves (18 KB)

  // head-locality swizzle: nid -> (bh, qt) with bh % 8 == nid % 8
  const int nid = blockIdx.x;
  const int b7 = nid & 7, rest = nid >> 3;
  const int qt = rest & 7;
  const int bh = b7 + ((rest >> 3) << 3);

  const int t = threadIdx.x, lane = t & 63, w = t >> 6;
  const int rl = lane & 15, gs = lane >> 4;
  const int q0 = qt * 128 + w * 32;
  const __bf16* Qh = Q  + (size_t)bh * 1024 * 64;
  const char*   Kg = (const char*)(Kb + (size_t)bh * 1024 * 64);
  const char*   Vg = (const char*)(Vt + (size_t)bh * 64 * 1024);
  __bf16* Pw = &P_lds[w][0];

  // staging granule geometry (per thread: 2 K + 2 V 16B-granules per tile)
  const int g0 = w * 64 + lane;         // 0..255
  const int g1 = 256 + g0;              // 256..511
  const int r0 = g0 >> 3, sb0 = (g0 & 7) ^ (r0 & 7);
  const int r1 = g1 >> 3, sb1 = (g1 & 7) ^ (r1 & 7);

  // Q fragments in registers (held for whole kernel)
  bf16x8 aq[2][2];
  #pragma unroll
  for (int m = 0; m < 2; ++m)
    #pragma unroll
    for (int ks = 0; ks < 2; ++ks)
      aq[m][ks] = *(const bf16x8*)(Qh + (size_t)(q0 + m * 16 + rl) * 64 + ks * 32 + gs * 8);

  f32x4 accO[2][4];
  #pragma unroll
  for (int m = 0; m < 2; ++m)
    #pragma unroll
    for (int d = 0; d < 4; ++d) accO[m][d] = { 0.f, 0.f, 0.f, 0.f };
  float L[2][4];
  #pragma unroll
  for (int m = 0; m < 2; ++m)
    #pragma unroll
    for (int b = 0; b < 4; ++b) L[m][b] = 0.f;

  // prologue: stage tile 0 into buffer 0
  {
    gload16(Kg + (size_t)r0 * 128 + sb0 * 16, (char*)Ks[0] + g0 * 16);
    gload16(Kg + (size_t)r1 * 128 + sb1 * 16, (char*)Ks[0] + g1 * 16);
    gload16(Vg + (size_t)r0 * 2048 + sb0 * 16, (char*)Vs[0] + g0 * 16);
    gload16(Vg + (size_t)r1 * 2048 + sb1 * 16, (char*)Vs[0] + g1 * 16);
  }

  for (int tile = 0; tile < 16; ++tile) {
    const int cur = tile & 1;
    if (tile + 1 < 16) {
      const int nxt = cur ^ 1;
      const size_t kofs = (size_t)(tile + 1) * 64;
      gload16(Kg + (kofs + r0) * 128 + sb0 * 16, (char*)Ks[nxt] + g0 * 16);
      gload16(Kg + (kofs + r1) * 128 + sb1 * 16, (char*)Ks[nxt] + g1 * 16);
      gload16(Vg + (size_t)r0 * 2048 + kofs * 2 + sb0 * 16, (char*)Vs[nxt] + g0 * 16);
      gload16(Vg + (size_t)r1 * 2048 + kofs * 2 + sb1 * 16, (char*)Vs[nxt] + g1 * 16);
      WAIT_VM4();   // oldest 4 (current tile) landed; next tile stays in flight
    } else {
      WAIT_VM0();
    }
    S_BARRIER();    // current tile visible to all waves

    const __bf16* Kc = Ks[cur];
    const __bf16* Vc = Vs[cur];

    // ---- S = Q @ K^T : 32 q-rows x 64 keys ----
    f32x4 s[2][4];
    #pragma unroll
    for (int m = 0; m < 2; ++m)
      #pragma unroll
      for (int ct = 0; ct < 4; ++ct) s[m][ct] = { 0.f, 0.f, 0.f, 0.f };
    __builtin_amdgcn_s_setprio(1);
    #pragma unroll
    for (int ct = 0; ct < 4; ++ct) {
      #pragma unroll
      for (int ks = 0; ks < 2; ++ks) {
        const int row = ct * 16 + rl;
        const int blk = (ks * 4 + gs) ^ (row & 7);
        bf16x8 kf = *(const bf16x8*)(Kc + row * 64 + blk * 8);
        s[0][ct] = __builtin_amdgcn_mfma_f32_16x16x32_bf16(aq[0][ks], kf, s[0][ct], 0, 0, 0);
        s[1][ct] = __builtin_amdgcn_mfma_f32_16x16x32_bf16(aq[1][ks], kf, s[1][ct], 0, 0, 0);
      }
    }
    __builtin_amdgcn_s_setprio(0);

    // ---- P = exp2(S'), local denom accumulate; no max, no rescale, no shuffles ----
    #pragma unroll
    for (int m = 0; m < 2; ++m) {
      #pragma unroll
      for (int b = 0; b < 4; ++b) {
        float rs = 0.f;
        #pragma unroll
        for (int ct = 0; ct < 4; ++ct) {
          const float p = exp2_fast(s[m][ct][b]);
          rs += p;
          Pw[(m * 16 + gs * 4 + b) * 72 + ct * 16 + rl] = (__bf16)p;
        }
        L[m][b] += rs;
      }
    }

    WAIT_LGKM();    // all 64 lanes' P writes visible before cross-lane reads
    bf16x8 ap[2][2];
    #pragma unroll
    for (int m = 0; m < 2; ++m)
      #pragma unroll
      for (int ks = 0; ks < 2; ++ks)
        ap[m][ks] = *(const bf16x8*)(Pw + (m * 16 + rl) * 72 + ks * 32 + gs * 8);

    // ---- O += P @ V ----
    __builtin_amdgcn_s_setprio(1);
    #pragma unroll
    for (int dt = 0; dt < 4; ++dt) {
      #pragma unroll
      for (int ks = 0; ks < 2; ++ks) {
        const int row = dt * 16 + rl;
        const int blk = (ks * 4 + gs) ^ (row & 7);
        bf16x8 vf = *(const bf16x8*)(Vc + row * 64 + blk * 8);
        accO[0][dt] = __builtin_amdgcn_mfma_f32_16x16x32_bf16(ap[0][ks], vf, accO[0][dt], 0, 0, 0);
        accO[1][dt] = __builtin_amdgcn_mfma_f32_16x16x32_bf16(ap[1][ks], vf, accO[1][dt], 0, 0, 0);
      }
    }
    __builtin_amdgcn_s_setprio(0);

    S_BARRIER();    // all waves done reading tile before it is overwritten
  }

  // final denominator: reduce per-lane partial sums across the 16 rl-lanes (once)
  float invL[2][4];
  #pragma unroll
  for (int m = 0; m < 2; ++m)
    #pragma unroll
    for (int b = 0; b < 4; ++b) {
      float rs = L[m][b];
      #pragma unroll
      for (int off = 1; off < 16; off <<= 1) rs += __shfl_xor(rs, off, 16);
      invL[m][b] = 1.0f / rs;
    }

  const int batch = bh / 12, hh = bh - batch * 12;
  #pragma unroll
  for (int m = 0; m < 2; ++m) {
    const size_t rowbase = (size_t)batch * 1024 + qt * 128 + w * 32 + m * 16 + gs * 4;
    #pragma unroll
    for (int dt = 0; dt < 4; ++dt)
      #pragma unroll
      for (int b = 0; b < 4; ++b)
        Ob[(rowbase + b) * 768 + hh * 64 + dt * 16 + rl] = (__bf16)(accO[m][dt][b] * invL[m][b]);
  }
}

// ---------------- launch ----------------
extern "C" void kernel_launch(void* const* d_in, const int* in_sizes, int n_in,
                              void* d_out, int out_size, void* d_ws, size_t ws_size,
                              hipStream_t stream) {
  const float* x      = (const float*)d_in[0];
  const float* ln1_g  = (const float*)d_in[1];
  const float* ln1_b  = (const float*)d_in[2];
  const float* w_qkv  = (const float*)d_in[3];
  const float* w_proj = (const float*)d_in[4];
  const float* b_proj = (const float*)d_in[5];
  const float* ls1    = (const float*)d_in[6];
  const float* ln2_g  = (const float*)d_in[7];
  const float* ln2_b  = (const float*)d_in[8];
  const float* w_fc1  = (const float*)d_in[9];
  const float* b_fc1  = (const float*)d_in[10];
  const float* w_fc2  = (const float*)d_in[11];
  const float* b_fc2  = (const float*)d_in[12];
  const float* ls2    = (const float*)d_in[13];
  float* out = (float*)d_out;

  char* ws = (char*)d_ws;
  size_t off = 0;
  auto alloc = [&](size_t bytes) { char* p = ws + off; off += (bytes + 255) & ~(size_t)255; return p; };
  __bf16* h1    = (__bf16*)alloc(8192ull * 768 * 2);   // LN1 out; later reused as attn_out
  __bf16* wqkvb = (__bf16*)alloc(2304ull * 768 * 2);
  __bf16* wprjb = (__bf16*)alloc(768ull * 768 * 2);
  __bf16* wfc1b = (__bf16*)alloc(3072ull * 768 * 2);
  __bf16* wfc2b = (__bf16*)alloc(768ull * 3072 * 2);
  __bf16* Qb    = (__bf16*)alloc(8192ull * 768 * 2);   // later reused as h2
  __bf16* Kb    = (__bf16*)alloc(8192ull * 768 * 2);
  __bf16* Vt    = (__bf16*)alloc(8192ull * 768 * 2);
  float*  out1  = (float*)alloc(8192ull * 768 * 4);
  __bf16* fc1o  = (__bf16*)alloc(8192ull * 3072 * 2);

  ln_kernel<<<8192, 256, 0, stream>>>(x, ln1_g, ln1_b, h1);
  cast4_kernel<<<2048, 256, 0, stream>>>(w_qkv, w_proj, w_fc1, w_fc2,
                                         wqkvb, wprjb, wfc1b, wfc2b);

  gemm_kernel<0, 128, 128><<<dim3(18, 64), 256, 0, stream>>>(h1, wqkvb, 768,
      nullptr, nullptr, nullptr, nullptr, nullptr, Qb, Kb, Vt);

  attn_kernel<<<96 * 8, 256, 0, stream>>>(Qb, Kb, Vt, h1);  // h1 = attn_out now

  gemm_kernel<1, 64, 64><<<dim3(12, 128), 256, 0, stream>>>(h1, wprjb, 768,
      b_proj, x, ls1, out1, nullptr, nullptr, nullptr, nullptr);

  ln_kernel<<<8192, 256, 0, stream>>>(out1, ln2_g, ln2_b, Qb);  // Qb = h2 now

  gemm_kernel<2, 128, 128><<<dim3(24, 64), 256, 0, stream>>>(Qb, wfc1b, 768,
      b_fc1, nullptr, nullptr, nullptr, fc1o, nullptr, nullptr, nullptr);

  gemm_kernel<3, 64, 64><<<dim3(12, 128), 256, 0, stream>>>(fc1o, wfc2b, 3072,
      b_fc2, out1, ls2, out, nullptr, nullptr, nullptr, nullptr);
}

// Round 9
// 261.105 us; speedup vs baseline: 1.1463x; 1.1463x over previous
//
#include <hip/hip_runtime.h>
#include <cstdint>
#include <cstddef>

typedef __bf16 bf16x8 __attribute__((ext_vector_type(8)));
typedef __bf16 bf16x4 __attribute__((ext_vector_type(4)));
typedef float f32x4 __attribute__((ext_vector_type(4)));

__device__ __forceinline__ void gload16(const void* g, void* l) {
  __builtin_amdgcn_global_load_lds((const __attribute__((address_space(1))) void*)g,
                                   (__attribute__((address_space(3))) void*)l, 16, 0, 0);
}

__device__ __forceinline__ float exp2_fast(float x) {
  float r;
  asm("v_exp_f32 %0, %1" : "=v"(r) : "v"(x));
  return r;
}
__device__ __forceinline__ float rcp_fast(float x) {
  float r;
  asm("v_rcp_f32 %0, %1" : "=v"(r) : "v"(x));
  return r;
}

template<int N> __device__ __forceinline__ void wait_vm() {
  if constexpr (N == 0) asm volatile("s_waitcnt vmcnt(0)" ::: "memory");
  else if constexpr (N == 4) asm volatile("s_waitcnt vmcnt(4)" ::: "memory");
  else if constexpr (N == 6) asm volatile("s_waitcnt vmcnt(6)" ::: "memory");
  else if constexpr (N == 8) asm volatile("s_waitcnt vmcnt(8)" ::: "memory");
}

#define S_BARRIER() __builtin_amdgcn_s_barrier()
#define WAIT_VM4()  asm volatile("s_waitcnt vmcnt(4)" ::: "memory")
#define WAIT_VM0()  asm volatile("s_waitcnt vmcnt(0)" ::: "memory")
#define WAIT_LGKM() asm volatile("s_waitcnt lgkmcnt(0)" ::: "memory")

// ---------------- LayerNorm: fp32 in -> bf16 out (row = 768) ----------------
__global__ __launch_bounds__(256) void ln_kernel(const float* __restrict__ x,
    const float* __restrict__ g, const float* __restrict__ b,
    __bf16* __restrict__ out)
{
  __shared__ float red[8];
  const int row = blockIdx.x, t = threadIdx.x;
  const float* xr = x + (size_t)row * 768;
  float v0 = xr[t], v1 = xr[t + 256], v2 = xr[t + 512];
  float s = v0 + v1 + v2;
  float q = v0 * v0 + v1 * v1 + v2 * v2;
  #pragma unroll
  for (int off = 32; off > 0; off >>= 1) {
    s += __shfl_xor(s, off, 64);
    q += __shfl_xor(q, off, 64);
  }
  const int w = t >> 6;
  if ((t & 63) == 0) { red[w] = s; red[4 + w] = q; }
  __syncthreads();
  s = red[0] + red[1] + red[2] + red[3];
  q = red[4] + red[5] + red[6] + red[7];
  const float mu = s * (1.0f / 768.0f);
  const float var = q * (1.0f / 768.0f) - mu * mu;
  const float rstd = rsqrtf(var + 1e-5f);
  __bf16* orow = out + (size_t)row * 768;
  orow[t]       = (__bf16)((v0 - mu) * rstd * g[t]       + b[t]);
  orow[t + 256] = (__bf16)((v1 - mu) * rstd * g[t + 256] + b[t + 256]);
  orow[t + 512] = (__bf16)((v2 - mu) * rstd * g[t + 512] + b[t + 512]);
}

// ---------------- fused fp32 -> bf16 cast of all 4 weight matrices ----------------
__global__ __launch_bounds__(256) void cast4_kernel(
    const float* __restrict__ i0, const float* __restrict__ i1,
    const float* __restrict__ i2, const float* __restrict__ i3,
    __bf16* __restrict__ o0, __bf16* __restrict__ o1,
    __bf16* __restrict__ o2, __bf16* __restrict__ o3)
{
  const int n0 = 2304 * 768 / 4, n1 = 768 * 768 / 4;
  const int n2 = 3072 * 768 / 4, n3 = 768 * 3072 / 4;
  const int total = n0 + n1 + n2 + n3;
  for (int i = blockIdx.x * 256 + threadIdx.x; i < total; i += gridDim.x * 256) {
    const float* in; __bf16* out; int j = i;
    if (j < n0) { in = i0; out = o0; }
    else if ((j -= n0) < n1) { in = i1; out = o1; }
    else if ((j -= n1) < n2) { in = i2; out = o2; }
    else { j -= n2; in = i3; out = o3; }
    float4 v = ((const float4*)in)[j];
    bf16x4 o = { (__bf16)v.x, (__bf16)v.y, (__bf16)v.z, (__bf16)v.w };
    ((bf16x4*)out)[j] = o;
  }
}

// ---------------- GEMM v7: C[M,N] = A[M,K](bf16) @ W[N,K]^T(bf16) ----------------
// BMxBNxBK tile, 4 waves (2x2), 16x16x32 bf16 MFMA.
//   128x128x32: NBUF=3, depth-2, vmcnt(8), 48 KB  (QKV, FC1 — r7-proven)
//   128x 64x64: NBUF=2, depth-1, vmcnt(6), 48 KB  (proj, FC2 — 16 MFMA per
//               barrier-pair, half the iterations: barrier-overhead/FLOP halved)
// Generic granule XOR-swizzle on LDS rows (pre-swizzled global source +
// swizzled read; BK=32 rows: XOR (row>>1)&3, BK=64 rows: XOR row&7) -> ~0 conflicts.
// XCD-aware bijective block swizzle (grids all %8==0).
// MODE 0: QKV scatter (Q scaled 0.125*log2e, V transposed). MODE 1: proj (+bias, resid+ls).
// MODE 2: fc1 (+bias, fast GELU -> bf16). MODE 3: fc2 (+bias, resid+ls -> f32).
template<int MODE, int BM, int BN, int BK>
__global__ __launch_bounds__(256) void gemm_kernel(
    const __bf16* __restrict__ A, const __bf16* __restrict__ W, int K,
    const float* __restrict__ bias, const float* __restrict__ resid,
    const float* __restrict__ ls, float* __restrict__ outf,
    __bf16* __restrict__ outb,
    __bf16* __restrict__ qo, __bf16* __restrict__ ko, __bf16* __restrict__ vo)
{
  constexpr int FM = BM / 32;            // m-fragments per wave
  constexpr int FN = BN / 32;            // n-fragments per wave
  constexpr int KS = BK / 32;            // k-substeps per tile
  constexpr int WMS = BM / 2;
  constexpr int WNS = BN / 2;
  constexpr int GPR = BK / 8;            // 16B granules per LDS row
  constexpr int AG = BM * BK / 2048;     // A granules per thread per stage
  constexpr int BG = BN * BK / 2048;     // B granules per thread per stage
  constexpr int LPT = AG + BG;           // global_load_lds per stage
  constexpr int NBUF = (BK == 64) ? 2 : 3;
  constexpr int DEPTH = NBUF - 1;
  constexpr int ASTRIDE = BM * BK;
  constexpr int BSTRIDE = BN * BK;
  __shared__ __bf16 As[NBUF * ASTRIDE];
  __shared__ __bf16 Bs[NBUF * BSTRIDE];

  // XCD-aware swizzle of the linear block id (bijective: nwg % 8 == 0)
  const int nx = gridDim.x;
  const int nwg = nx * gridDim.y;
  const int orig = blockIdx.x + nx * blockIdx.y;
  const int nid = (orig & 7) * (nwg >> 3) + (orig >> 3);
  const int bx = nid % nx, by = nid / nx;

  const int t = threadIdx.x;
  const int lane = t & 63;
  const int w = t >> 6;
  const int wm = w >> 1, wn = w & 1;
  const int m0 = by * BM, n0 = bx * BN;
  const int rl = lane & 15, gs = lane >> 4;

  // row-dependent granule swizzle (matches bank geometry of the row stride)
  auto swz = [](int row) -> int {
    if constexpr (BK == 32) return (row >> 1) & 3;
    else                    return row & 7;
  };

  f32x4 acc[FM][FN];
  #pragma unroll
  for (int i = 0; i < FM; ++i)
    #pragma unroll
    for (int j = 0; j < FN; ++j) acc[i][j] = { 0.f, 0.f, 0.f, 0.f };

  // per-granule staging sources (pre-swizzled column within the K-slab)
  const __bf16* Asrc[AG];
  const __bf16* Bsrc[BG];
  #pragma unroll
  for (int i = 0; i < AG; ++i) {
    const int g = i * 256 + t, row = g / GPR, gr = g % GPR;
    Asrc[i] = A + (size_t)(m0 + row) * K + (gr ^ swz(row)) * 8;
  }
  #pragma unroll
  for (int i = 0; i < BG; ++i) {
    const int g = i * 256 + t, row = g / GPR, gr = g % GPR;
    Bsrc[i] = W + (size_t)(n0 + row) * K + (gr ^ swz(row)) * 8;
  }

  auto stage = [&](int kt, int buf) {
    const int k0 = kt * BK;
    #pragma unroll
    for (int i = 0; i < AG; ++i)
      gload16(Asrc[i] + k0, As + buf * ASTRIDE + (i * 256 + t) * 8);
    #pragma unroll
    for (int i = 0; i < BG; ++i)
      gload16(Bsrc[i] + k0, Bs + buf * BSTRIDE + (i * 256 + t) * 8);
  };

  const int nk = K / BK;
  #pragma unroll
  for (int i = 0; i < DEPTH; ++i) stage(i, i);

  auto body = [&](int kt) {
    const int cur = kt % NBUF;
    if (kt + DEPTH < nk) { stage(kt + DEPTH, (kt + DEPTH) % NBUF); wait_vm<LPT * DEPTH>(); }
    else if constexpr (DEPTH == 2) {
      if (kt + 1 < nk) wait_vm<LPT>(); else wait_vm<0>();
    } else {
      wait_vm<0>();
    }
    S_BARRIER();                  // tile kt resident for all waves

    const __bf16* Ac = As + cur * ASTRIDE;
    const __bf16* Bc = Bs + cur * BSTRIDE;
    bf16x8 af[FM][KS], bfr[FN][KS];
    #pragma unroll
    for (int fm = 0; fm < FM; ++fm) {
      const int row = wm * WMS + fm * 16 + rl;
      #pragma unroll
      for (int ks = 0; ks < KS; ++ks)
        af[fm][ks] = *(const bf16x8*)(Ac + row * BK + ((ks * 4 + gs) ^ swz(row)) * 8);
    }
    #pragma unroll
    for (int fn = 0; fn < FN; ++fn) {
      const int row = wn * WNS + fn * 16 + rl;
      #pragma unroll
      for (int ks = 0; ks < KS; ++ks)
        bfr[fn][ks] = *(const bf16x8*)(Bc + row * BK + ((ks * 4 + gs) ^ swz(row)) * 8);
    }
    #pragma unroll
    for (int ks = 0; ks < KS; ++ks)
      #pragma unroll
      for (int fm = 0; fm < FM; ++fm)
        #pragma unroll
        for (int fn = 0; fn < FN; ++fn)
          acc[fm][fn] = __builtin_amdgcn_mfma_f32_16x16x32_bf16(af[fm][ks], bfr[fn][ks], acc[fm][fn], 0, 0, 0);

    S_BARRIER();                  // all waves done with tile kt before re-staging
  };

  if constexpr (NBUF == 2) {
    #pragma unroll 2
    for (int kt = 0; kt < nk; ++kt) body(kt);
  } else {
    #pragma unroll 3
    for (int kt = 0; kt < nk; ++kt) body(kt);
  }

  // epilogue: C row = m0+wm*WMS+fm*16+gs*4+b ; col = n0+wn*WNS+fn*16+rl
  #pragma unroll
  for (int fm = 0; fm < FM; ++fm) {
    const int rbase = m0 + wm * WMS + fm * 16 + gs * 4;
    #pragma unroll
    for (int fn = 0; fn < FN; ++fn) {
      const int c = n0 + wn * WNS + fn * 16 + rl;
      #pragma unroll
      for (int b = 0; b < 4; ++b) {
        const int r = rbase + b;
        const float val = acc[fm][fn][b];
        if constexpr (MODE == 0) {
          const int sec = c / 768;
          const int cc = c - sec * 768;
          const int hh = cc >> 6, d = cc & 63;
          const int batch = r >> 10, n = r & 1023;
          const size_t bh = (size_t)(batch * 12 + hh);
          // Q scaled by (1/8)*log2(e) so softmax uses raw v_exp_f32 (2^x)
          if (sec == 0)      qo[(bh * 1024 + n) * 64 + d] = (__bf16)(val * 0.1803368801111204f);
          else if (sec == 1) ko[(bh * 1024 + n) * 64 + d] = (__bf16)val;
          else               vo[(bh * 64 + d) * 1024 + n] = (__bf16)val;
        } else if constexpr (MODE == 1) {
          const size_t idx = (size_t)r * 768 + c;
          outf[idx] = resid[idx] + ls[c] * (val + bias[c]);
        } else if constexpr (MODE == 2) {
          // fast GELU: h*sigmoid(2*0.7978845608*(h+0.044715 h^3)), exp2-folded.
          const float h = val + bias[c];
          const float z = h * (1.0f + 0.044715f * h * h);
          const float e = exp2_fast(2.3021181f * z);   // 2*0.79788456*log2(e) * z
          const float gl = h - h * rcp_fast(1.0f + e);
          outb[(size_t)r * 3072 + c] = (__bf16)gl;
        } else {
          const size_t idx = (size_t)r * 768 + c;
          outf[idx] = resid[idx] + ls[c] * (val + bias[c]);
        }
      }
    }
  }
}

// ---------------- Flash attention (fixed-max exp2 softmax, deferred denom) ----
// Q: [96][1024][64] bf16 pre-scaled by 0.125*log2e. K: [96][1024][64]. Vt: [96][64][1024].
// Block-id mapping puts all 8 q-tiles of a head on one XCD (12 heads x 256KB = 3MB < 4MB L2).
__global__ __launch_bounds__(256, 3) void attn_kernel(
    const __bf16* __restrict__ Q, const __bf16* __restrict__ Kb,
    const __bf16* __restrict__ Vt, __bf16* __restrict__ Ob)
{
  __shared__ __bf16 Ks[2][64 * 64];     // 2 x 8 KB
  __shared__ __bf16 Vs[2][64 * 64];     // 2 x 8 KB
  __shared__ __bf16 P_lds[4][32 * 72];  // per-wave P, rows padded to 72 halves (18 KB)

  // head-locality swizzle: nid -> (bh, qt) with bh % 8 == nid % 8
  const int nid = blockIdx.x;
  const int b7 = nid & 7, rest = nid >> 3;
  const int qt = rest & 7;
  const int bh = b7 + ((rest >> 3) << 3);

  const int t = threadIdx.x, lane = t & 63, w = t >> 6;
  const int rl = lane & 15, gs = lane >> 4;
  const int q0 = qt * 128 + w * 32;
  const __bf16* Qh = Q  + (size_t)bh * 1024 * 64;
  const char*   Kg = (const char*)(Kb + (size_t)bh * 1024 * 64);
  const char*   Vg = (const char*)(Vt + (size_t)bh * 64 * 1024);
  __bf16* Pw = &P_lds[w][0];

  // staging granule geometry (per thread: 2 K + 2 V 16B-granules per tile)
  const int g0 = w * 64 + lane;         // 0..255
  const int g1 = 256 + g0;              // 256..511
  const int r0 = g0 >> 3, sb0 = (g0 & 7) ^ (r0 & 7);
  const int r1 = g1 >> 3, sb1 = (g1 & 7) ^ (r1 & 7);

  // Q fragments in registers (held for whole kernel)
  bf16x8 aq[2][2];
  #pragma unroll
  for (int m = 0; m < 2; ++m)
    #pragma unroll
    for (int ks = 0; ks < 2; ++ks)
      aq[m][ks] = *(const bf16x8*)(Qh + (size_t)(q0 + m * 16 + rl) * 64 + ks * 32 + gs * 8);

  f32x4 accO[2][4];
  #pragma unroll
  for (int m = 0; m < 2; ++m)
    #pragma unroll
    for (int d = 0; d < 4; ++d) accO[m][d] = { 0.f, 0.f, 0.f, 0.f };
  float L[2][4];
  #pragma unroll
  for (int m = 0; m < 2; ++m)
    #pragma unroll
    for (int b = 0; b < 4; ++b) L[m][b] = 0.f;

  // prologue: stage tile 0 into buffer 0
  {
    gload16(Kg + (size_t)r0 * 128 + sb0 * 16, (char*)Ks[0] + g0 * 16);
    gload16(Kg + (size_t)r1 * 128 + sb1 * 16, (char*)Ks[0] + g1 * 16);
    gload16(Vg + (size_t)r0 * 2048 + sb0 * 16, (char*)Vs[0] + g0 * 16);
    gload16(Vg + (size_t)r1 * 2048 + sb1 * 16, (char*)Vs[0] + g1 * 16);
  }

  for (int tile = 0; tile < 16; ++tile) {
    const int cur = tile & 1;
    if (tile + 1 < 16) {
      const int nxt = cur ^ 1;
      const size_t kofs = (size_t)(tile + 1) * 64;
      gload16(Kg + (kofs + r0) * 128 + sb0 * 16, (char*)Ks[nxt] + g0 * 16);
      gload16(Kg + (kofs + r1) * 128 + sb1 * 16, (char*)Ks[nxt] + g1 * 16);
      gload16(Vg + (size_t)r0 * 2048 + kofs * 2 + sb0 * 16, (char*)Vs[nxt] + g0 * 16);
      gload16(Vg + (size_t)r1 * 2048 + kofs * 2 + sb1 * 16, (char*)Vs[nxt] + g1 * 16);
      WAIT_VM4();   // oldest 4 (current tile) landed; next tile stays in flight
    } else {
      WAIT_VM0();
    }
    S_BARRIER();    // current tile visible to all waves

    const __bf16* Kc = Ks[cur];
    const __bf16* Vc = Vs[cur];

    // ---- S = Q @ K^T : 32 q-rows x 64 keys ----
    f32x4 s[2][4];
    #pragma unroll
    for (int m = 0; m < 2; ++m)
      #pragma unroll
      for (int ct = 0; ct < 4; ++ct) s[m][ct] = { 0.f, 0.f, 0.f, 0.f };
    __builtin_amdgcn_s_setprio(1);
    #pragma unroll
    for (int ct = 0; ct < 4; ++ct) {
      #pragma unroll
      for (int ks = 0; ks < 2; ++ks) {
        const int row = ct * 16 + rl;
        const int blk = (ks * 4 + gs) ^ (row & 7);
        bf16x8 kf = *(const bf16x8*)(Kc + row * 64 + blk * 8);
        s[0][ct] = __builtin_amdgcn_mfma_f32_16x16x32_bf16(aq[0][ks], kf, s[0][ct], 0, 0, 0);
        s[1][ct] = __builtin_amdgcn_mfma_f32_16x16x32_bf16(aq[1][ks], kf, s[1][ct], 0, 0, 0);
      }
    }
    __builtin_amdgcn_s_setprio(0);

    // ---- P = exp2(S'), local denom accumulate; no max, no rescale, no shuffles ----
    #pragma unroll
    for (int m = 0; m < 2; ++m) {
      #pragma unroll
      for (int b = 0; b < 4; ++b) {
        float rs = 0.f;
        #pragma unroll
        for (int ct = 0; ct < 4; ++ct) {
          const float p = exp2_fast(s[m][ct][b]);
          rs += p;
          Pw[(m * 16 + gs * 4 + b) * 72 + ct * 16 + rl] = (__bf16)p;
        }
        L[m][b] += rs;
      }
    }

    WAIT_LGKM();    // all 64 lanes' P writes visible before cross-lane reads
    bf16x8 ap[2][2];
    #pragma unroll
    for (int m = 0; m < 2; ++m)
      #pragma unroll
      for (int ks = 0; ks < 2; ++ks)
        ap[m][ks] = *(const bf16x8*)(Pw + (m * 16 + rl) * 72 + ks * 32 + gs * 8);

    // ---- O += P @ V ----
    __builtin_amdgcn_s_setprio(1);
    #pragma unroll
    for (int dt = 0; dt < 4; ++dt) {
      #pragma unroll
      for (int ks = 0; ks < 2; ++ks) {
        const int row = dt * 16 + rl;
        const int blk = (ks * 4 + gs) ^ (row & 7);
        bf16x8 vf = *(const bf16x8*)(Vc + row * 64 + blk * 8);
        accO[0][dt] = __builtin_amdgcn_mfma_f32_16x16x32_bf16(ap[0][ks], vf, accO[0][dt], 0, 0, 0);
        accO[1][dt] = __builtin_amdgcn_mfma_f32_16x16x32_bf16(ap[1][ks], vf, accO[1][dt], 0, 0, 0);
      }
    }
    __builtin_amdgcn_s_setprio(0);

    S_BARRIER();    // all waves done reading tile before it is overwritten
  }

  // final denominator: reduce per-lane partial sums across the 16 rl-lanes (once)
  float invL[2][4];
  #pragma unroll
  for (int m = 0; m < 2; ++m)
    #pragma unroll
    for (int b = 0; b < 4; ++b) {
      float rs = L[m][b];
      #pragma unroll
      for (int off = 1; off < 16; off <<= 1) rs += __shfl_xor(rs, off, 16);
      invL[m][b] = 1.0f / rs;
    }

  const int batch = bh / 12, hh = bh - batch * 12;
  #pragma unroll
  for (int m = 0; m < 2; ++m) {
    const size_t rowbase = (size_t)batch * 1024 + qt * 128 + w * 32 + m * 16 + gs * 4;
    #pragma unroll
    for (int dt = 0; dt < 4; ++dt)
      #pragma unroll
      for (int b = 0; b < 4; ++b)
        Ob[(rowbase + b) * 768 + hh * 64 + dt * 16 + rl] = (__bf16)(accO[m][dt][b] * invL[m][b]);
  }
}

// ---------------- launch ----------------
extern "C" void kernel_launch(void* const* d_in, const int* in_sizes, int n_in,
                              void* d_out, int out_size, void* d_ws, size_t ws_size,
                              hipStream_t stream) {
  const float* x      = (const float*)d_in[0];
  const float* ln1_g  = (const float*)d_in[1];
  const float* ln1_b  = (const float*)d_in[2];
  const float* w_qkv  = (const float*)d_in[3];
  const float* w_proj = (const float*)d_in[4];
  const float* b_proj = (const float*)d_in[5];
  const float* ls1    = (const float*)d_in[6];
  const float* ln2_g  = (const float*)d_in[7];
  const float* ln2_b  = (const float*)d_in[8];
  const float* w_fc1  = (const float*)d_in[9];
  const float* b_fc1  = (const float*)d_in[10];
  const float* w_fc2  = (const float*)d_in[11];
  const float* b_fc2  = (const float*)d_in[12];
  const float* ls2    = (const float*)d_in[13];
  float* out = (float*)d_out;

  char* ws = (char*)d_ws;
  size_t off = 0;
  auto alloc = [&](size_t bytes) { char* p = ws + off; off += (bytes + 255) & ~(size_t)255; return p; };
  __bf16* h1    = (__bf16*)alloc(8192ull * 768 * 2);   // LN1 out; later reused as attn_out
  __bf16* wqkvb = (__bf16*)alloc(2304ull * 768 * 2);
  __bf16* wprjb = (__bf16*)alloc(768ull * 768 * 2);
  __bf16* wfc1b = (__bf16*)alloc(3072ull * 768 * 2);
  __bf16* wfc2b = (__bf16*)alloc(768ull * 3072 * 2);
  __bf16* Qb    = (__bf16*)alloc(8192ull * 768 * 2);   // later reused as h2
  __bf16* Kb    = (__bf16*)alloc(8192ull * 768 * 2);
  __bf16* Vt    = (__bf16*)alloc(8192ull * 768 * 2);
  float*  out1  = (float*)alloc(8192ull * 768 * 4);
  __bf16* fc1o  = (__bf16*)alloc(8192ull * 3072 * 2);

  ln_kernel<<<8192, 256, 0, stream>>>(x, ln1_g, ln1_b, h1);
  cast4_kernel<<<2048, 256, 0, stream>>>(w_qkv, w_proj, w_fc1, w_fc2,
                                         wqkvb, wprjb, wfc1b, wfc2b);

  gemm_kernel<0, 128, 128, 32><<<dim3(18, 64), 256, 0, stream>>>(h1, wqkvb, 768,
      nullptr, nullptr, nullptr, nullptr, nullptr, Qb, Kb, Vt);

  attn_kernel<<<96 * 8, 256, 0, stream>>>(Qb, Kb, Vt, h1);  // h1 = attn_out now

  gemm_kernel<1, 128, 64, 64><<<dim3(12, 64), 256, 0, stream>>>(h1, wprjb, 768,
      b_proj, x, ls1, out1, nullptr, nullptr, nullptr, nullptr);

  ln_kernel<<<8192, 256, 0, stream>>>(out1, ln2_g, ln2_b, Qb);  // Qb = h2 now

  gemm_kernel<2, 128, 128, 32><<<dim3(24, 64), 256, 0, stream>>>(Qb, wfc1b, 768,
      b_fc1, nullptr, nullptr, nullptr, fc1o, nullptr, nullptr, nullptr);

  gemm_kernel<3, 128, 64, 64><<<dim3(12, 64), 256, 0, stream>>>(fc1o, wfc2b, 3072,
      b_fc2, out1, ls2, out, nullptr, nullptr, nullptr, nullptr);
}

// Round 10
// 250.793 us; speedup vs baseline: 1.1934x; 1.0411x over previous
//
#include <hip/hip_runtime.h>
#include <cstdint>
#include <cstddef>

typedef __bf16 bf16x8 __attribute__((ext_vector_type(8)));
typedef __bf16 bf16x4 __attribute__((ext_vector_type(4)));
typedef float f32x4 __attribute__((ext_vector_type(4)));

__device__ __forceinline__ void gload16(const void* g, void* l) {
  __builtin_amdgcn_global_load_lds((const __attribute__((address_space(1))) void*)g,
                                   (__attribute__((address_space(3))) void*)l, 16, 0, 0);
}

__device__ __forceinline__ float exp2_fast(float x) {
  float r;
  asm("v_exp_f32 %0, %1" : "=v"(r) : "v"(x));
  return r;
}
__device__ __forceinline__ float rcp_fast(float x) {
  float r;
  asm("v_rcp_f32 %0, %1" : "=v"(r) : "v"(x));
  return r;
}

template<int N> __device__ __forceinline__ void wait_vm() {
  if constexpr (N == 0) asm volatile("s_waitcnt vmcnt(0)" ::: "memory");
  else if constexpr (N == 4) asm volatile("s_waitcnt vmcnt(4)" ::: "memory");
  else if constexpr (N == 6) asm volatile("s_waitcnt vmcnt(6)" ::: "memory");
  else if constexpr (N == 8) asm volatile("s_waitcnt vmcnt(8)" ::: "memory");
}

#define S_BARRIER() __builtin_amdgcn_s_barrier()
#define WAIT_VM4()  asm volatile("s_waitcnt vmcnt(4)" ::: "memory")
#define WAIT_VM0()  asm volatile("s_waitcnt vmcnt(0)" ::: "memory")
#define WAIT_LGKM() asm volatile("s_waitcnt lgkmcnt(0)" ::: "memory")

// ---------------- LayerNorm: fp32 in -> bf16 out (row = 768) ----------------
__global__ __launch_bounds__(256) void ln_kernel(const float* __restrict__ x,
    const float* __restrict__ g, const float* __restrict__ b,
    __bf16* __restrict__ out)
{
  __shared__ float red[8];
  const int row = blockIdx.x, t = threadIdx.x;
  const float* xr = x + (size_t)row * 768;
  float v0 = xr[t], v1 = xr[t + 256], v2 = xr[t + 512];
  float s = v0 + v1 + v2;
  float q = v0 * v0 + v1 * v1 + v2 * v2;
  #pragma unroll
  for (int off = 32; off > 0; off >>= 1) {
    s += __shfl_xor(s, off, 64);
    q += __shfl_xor(q, off, 64);
  }
  const int w = t >> 6;
  if ((t & 63) == 0) { red[w] = s; red[4 + w] = q; }
  __syncthreads();
  s = red[0] + red[1] + red[2] + red[3];
  q = red[4] + red[5] + red[6] + red[7];
  const float mu = s * (1.0f / 768.0f);
  const float var = q * (1.0f / 768.0f) - mu * mu;
  const float rstd = rsqrtf(var + 1e-5f);
  __bf16* orow = out + (size_t)row * 768;
  orow[t]       = (__bf16)((v0 - mu) * rstd * g[t]       + b[t]);
  orow[t + 256] = (__bf16)((v1 - mu) * rstd * g[t + 256] + b[t + 256]);
  orow[t + 512] = (__bf16)((v2 - mu) * rstd * g[t + 512] + b[t + 512]);
}

// ---------------- fused fp32 -> bf16 cast of all 4 weight matrices ----------------
__global__ __launch_bounds__(256) void cast4_kernel(
    const float* __restrict__ i0, const float* __restrict__ i1,
    const float* __restrict__ i2, const float* __restrict__ i3,
    __bf16* __restrict__ o0, __bf16* __restrict__ o1,
    __bf16* __restrict__ o2, __bf16* __restrict__ o3)
{
  const int n0 = 2304 * 768 / 4, n1 = 768 * 768 / 4;
  const int n2 = 3072 * 768 / 4, n3 = 768 * 3072 / 4;
  const int total = n0 + n1 + n2 + n3;
  for (int i = blockIdx.x * 256 + threadIdx.x; i < total; i += gridDim.x * 256) {
    const float* in; __bf16* out; int j = i;
    if (j < n0) { in = i0; out = o0; }
    else if ((j -= n0) < n1) { in = i1; out = o1; }
    else if ((j -= n1) < n2) { in = i2; out = o2; }
    else { j -= n2; in = i3; out = o3; }
    float4 v = ((const float4*)in)[j];
    bf16x4 o = { (__bf16)v.x, (__bf16)v.y, (__bf16)v.z, (__bf16)v.w };
    ((bf16x4*)out)[j] = o;
  }
}

// ---------------- GEMM v8: C[M,N] = A[M,K](bf16) @ W[N,K]^T(bf16) ----------------
// Uniform 128x64x64 tile, 4 waves (2x2), 16x16x32 bf16 MFMA.
// NBUF=2, depth-1 counted prefetch, vmcnt(6), 48 KB LDS (3 blocks/CU).
// 16 MFMA per wave per barrier-pair (r9-proven: barrier-overhead/FLOP is the lever).
// Grids: QKV 2304 (3 full rounds of 768), proj/FC2 768 (1 round), FC1 3072 (4 rounds).
// Granule XOR-swizzle (pre-swizzled global source + swizzled read) -> ~0 conflicts.
// XCD-aware bijective block swizzle (grids all %8==0).
// MODE 0: QKV scatter (Q scaled 0.125*log2e, V transposed; sec uniform per block).
// MODE 1: proj (+bias, resid+ls). MODE 2: fc1 (+bias, fast GELU -> bf16).
// MODE 3: fc2 (+bias, resid+ls -> f32).
template<int MODE, int BM, int BN, int BK>
__global__ __launch_bounds__(256) void gemm_kernel(
    const __bf16* __restrict__ A, const __bf16* __restrict__ W, int K,
    const float* __restrict__ bias, const float* __restrict__ resid,
    const float* __restrict__ ls, float* __restrict__ outf,
    __bf16* __restrict__ outb,
    __bf16* __restrict__ qo, __bf16* __restrict__ ko, __bf16* __restrict__ vo)
{
  constexpr int FM = BM / 32;            // m-fragments per wave
  constexpr int FN = BN / 32;            // n-fragments per wave
  constexpr int KS = BK / 32;            // k-substeps per tile
  constexpr int WMS = BM / 2;
  constexpr int WNS = BN / 2;
  constexpr int GPR = BK / 8;            // 16B granules per LDS row
  constexpr int AG = BM * BK / 2048;     // A granules per thread per stage
  constexpr int BG = BN * BK / 2048;     // B granules per thread per stage
  constexpr int LPT = AG + BG;           // global_load_lds per stage
  constexpr int NBUF = (BK == 64) ? 2 : 3;
  constexpr int DEPTH = NBUF - 1;
  constexpr int ASTRIDE = BM * BK;
  constexpr int BSTRIDE = BN * BK;
  __shared__ __bf16 As[NBUF * ASTRIDE];
  __shared__ __bf16 Bs[NBUF * BSTRIDE];

  // XCD-aware swizzle of the linear block id (bijective: nwg % 8 == 0)
  const int nx = gridDim.x;
  const int nwg = nx * gridDim.y;
  const int orig = blockIdx.x + nx * blockIdx.y;
  const int nid = (orig & 7) * (nwg >> 3) + (orig >> 3);
  const int bx = nid % nx, by = nid / nx;

  const int t = threadIdx.x;
  const int lane = t & 63;
  const int w = t >> 6;
  const int wm = w >> 1, wn = w & 1;
  const int m0 = by * BM, n0 = bx * BN;
  const int rl = lane & 15, gs = lane >> 4;

  // row-dependent granule swizzle (matches bank geometry of the row stride)
  auto swz = [](int row) -> int {
    if constexpr (BK == 32) return (row >> 1) & 3;
    else                    return row & 7;
  };

  f32x4 acc[FM][FN];
  #pragma unroll
  for (int i = 0; i < FM; ++i)
    #pragma unroll
    for (int j = 0; j < FN; ++j) acc[i][j] = { 0.f, 0.f, 0.f, 0.f };

  // per-granule staging sources (pre-swizzled column within the K-slab)
  const __bf16* Asrc[AG];
  const __bf16* Bsrc[BG];
  #pragma unroll
  for (int i = 0; i < AG; ++i) {
    const int g = i * 256 + t, row = g / GPR, gr = g % GPR;
    Asrc[i] = A + (size_t)(m0 + row) * K + (gr ^ swz(row)) * 8;
  }
  #pragma unroll
  for (int i = 0; i < BG; ++i) {
    const int g = i * 256 + t, row = g / GPR, gr = g % GPR;
    Bsrc[i] = W + (size_t)(n0 + row) * K + (gr ^ swz(row)) * 8;
  }

  auto stage = [&](int kt, int buf) {
    const int k0 = kt * BK;
    #pragma unroll
    for (int i = 0; i < AG; ++i)
      gload16(Asrc[i] + k0, As + buf * ASTRIDE + (i * 256 + t) * 8);
    #pragma unroll
    for (int i = 0; i < BG; ++i)
      gload16(Bsrc[i] + k0, Bs + buf * BSTRIDE + (i * 256 + t) * 8);
  };

  const int nk = K / BK;
  #pragma unroll
  for (int i = 0; i < DEPTH; ++i) stage(i, i);

  auto body = [&](int kt) {
    const int cur = kt % NBUF;
    if (kt + DEPTH < nk) { stage(kt + DEPTH, (kt + DEPTH) % NBUF); wait_vm<LPT * DEPTH>(); }
    else if constexpr (DEPTH == 2) {
      if (kt + 1 < nk) wait_vm<LPT>(); else wait_vm<0>();
    } else {
      wait_vm<0>();
    }
    S_BARRIER();                  // tile kt resident for all waves

    const __bf16* Ac = As + cur * ASTRIDE;
    const __bf16* Bc = Bs + cur * BSTRIDE;
    bf16x8 af[FM][KS], bfr[FN][KS];
    #pragma unroll
    for (int fm = 0; fm < FM; ++fm) {
      const int row = wm * WMS + fm * 16 + rl;
      #pragma unroll
      for (int ks = 0; ks < KS; ++ks)
        af[fm][ks] = *(const bf16x8*)(Ac + row * BK + ((ks * 4 + gs) ^ swz(row)) * 8);
    }
    #pragma unroll
    for (int fn = 0; fn < FN; ++fn) {
      const int row = wn * WNS + fn * 16 + rl;
      #pragma unroll
      for (int ks = 0; ks < KS; ++ks)
        bfr[fn][ks] = *(const bf16x8*)(Bc + row * BK + ((ks * 4 + gs) ^ swz(row)) * 8);
    }
    #pragma unroll
    for (int ks = 0; ks < KS; ++ks)
      #pragma unroll
      for (int fm = 0; fm < FM; ++fm)
        #pragma unroll
        for (int fn = 0; fn < FN; ++fn)
          acc[fm][fn] = __builtin_amdgcn_mfma_f32_16x16x32_bf16(af[fm][ks], bfr[fn][ks], acc[fm][fn], 0, 0, 0);

    S_BARRIER();                  // all waves done with tile kt before re-staging
  };

  if constexpr (NBUF == 2) {
    #pragma unroll 2
    for (int kt = 0; kt < nk; ++kt) body(kt);
  } else {
    #pragma unroll 3
    for (int kt = 0; kt < nk; ++kt) body(kt);
  }

  // epilogue: C row = m0+wm*WMS+fm*16+gs*4+b ; col = n0+wn*WNS+fn*16+rl
  #pragma unroll
  for (int fm = 0; fm < FM; ++fm) {
    const int rbase = m0 + wm * WMS + fm * 16 + gs * 4;
    #pragma unroll
    for (int fn = 0; fn < FN; ++fn) {
      const int c = n0 + wn * WNS + fn * 16 + rl;
      #pragma unroll
      for (int b = 0; b < 4; ++b) {
        const int r = rbase + b;
        const float val = acc[fm][fn][b];
        if constexpr (MODE == 0) {
          const int sec = c / 768;
          const int cc = c - sec * 768;
          const int hh = cc >> 6, d = cc & 63;
          const int batch = r >> 10, n = r & 1023;
          const size_t bh = (size_t)(batch * 12 + hh);
          // Q scaled by (1/8)*log2(e) so softmax uses raw v_exp_f32 (2^x)
          if (sec == 0)      qo[(bh * 1024 + n) * 64 + d] = (__bf16)(val * 0.1803368801111204f);
          else if (sec == 1) ko[(bh * 1024 + n) * 64 + d] = (__bf16)val;
          else               vo[(bh * 64 + d) * 1024 + n] = (__bf16)val;
        } else if constexpr (MODE == 1) {
          const size_t idx = (size_t)r * 768 + c;
          outf[idx] = resid[idx] + ls[c] * (val + bias[c]);
        } else if constexpr (MODE == 2) {
          // fast GELU: h*sigmoid(2*0.7978845608*(h+0.044715 h^3)), exp2-folded.
          const float h = val + bias[c];
          const float z = h * (1.0f + 0.044715f * h * h);
          const float e = exp2_fast(2.3021181f * z);   // 2*0.79788456*log2(e) * z
          const float gl = h - h * rcp_fast(1.0f + e);
          outb[(size_t)r * 3072 + c] = (__bf16)gl;
        } else {
          const size_t idx = (size_t)r * 768 + c;
          outf[idx] = resid[idx] + ls[c] * (val + bias[c]);
        }
      }
    }
  }
}

// ---------------- Flash attention (fixed-max exp2 softmax, deferred denom) ----
// Q: [96][1024][64] bf16 pre-scaled by 0.125*log2e. K: [96][1024][64]. Vt: [96][64][1024].
// Block-id mapping puts all 8 q-tiles of a head on one XCD (12 heads x 256KB = 3MB < 4MB L2).
__global__ __launch_bounds__(256, 3) void attn_kernel(
    const __bf16* __restrict__ Q, const __bf16* __restrict__ Kb,
    const __bf16* __restrict__ Vt, __bf16* __restrict__ Ob)
{
  __shared__ __bf16 Ks[2][64 * 64];     // 2 x 8 KB
  __shared__ __bf16 Vs[2][64 * 64];     // 2 x 8 KB
  __shared__ __bf16 P_lds[4][32 * 72];  // per-wave P, rows padded to 72 halves (18 KB)

  // head-locality swizzle: nid -> (bh, qt) with bh % 8 == nid % 8
  const int nid = blockIdx.x;
  const int b7 = nid & 7, rest = nid >> 3;
  const int qt = rest & 7;
  const int bh = b7 + ((rest >> 3) << 3);

  const int t = threadIdx.x, lane = t & 63, w = t >> 6;
  const int rl = lane & 15, gs = lane >> 4;
  const int q0 = qt * 128 + w * 32;
  const __bf16* Qh = Q  + (size_t)bh * 1024 * 64;
  const char*   Kg = (const char*)(Kb + (size_t)bh * 1024 * 64);
  const char*   Vg = (const char*)(Vt + (size_t)bh * 64 * 1024);
  __bf16* Pw = &P_lds[w][0];

  // staging granule geometry (per thread: 2 K + 2 V 16B-granules per tile)
  const int g0 = w * 64 + lane;         // 0..255
  const int g1 = 256 + g0;              // 256..511
  const int r0 = g0 >> 3, sb0 = (g0 & 7) ^ (r0 & 7);
  const int r1 = g1 >> 3, sb1 = (g1 & 7) ^ (r1 & 7);

  // Q fragments in registers (held for whole kernel)
  bf16x8 aq[2][2];
  #pragma unroll
  for (int m = 0; m < 2; ++m)
    #pragma unroll
    for (int ks = 0; ks < 2; ++ks)
      aq[m][ks] = *(const bf16x8*)(Qh + (size_t)(q0 + m * 16 + rl) * 64 + ks * 32 + gs * 8);

  f32x4 accO[2][4];
  #pragma unroll
  for (int m = 0; m < 2; ++m)
    #pragma unroll
    for (int d = 0; d < 4; ++d) accO[m][d] = { 0.f, 0.f, 0.f, 0.f };
  float L[2][4];
  #pragma unroll
  for (int m = 0; m < 2; ++m)
    #pragma unroll
    for (int b = 0; b < 4; ++b) L[m][b] = 0.f;

  // prologue: stage tile 0 into buffer 0
  {
    gload16(Kg + (size_t)r0 * 128 + sb0 * 16, (char*)Ks[0] + g0 * 16);
    gload16(Kg + (size_t)r1 * 128 + sb1 * 16, (char*)Ks[0] + g1 * 16);
    gload16(Vg + (size_t)r0 * 2048 + sb0 * 16, (char*)Vs[0] + g0 * 16);
    gload16(Vg + (size_t)r1 * 2048 + sb1 * 16, (char*)Vs[0] + g1 * 16);
  }

  for (int tile = 0; tile < 16; ++tile) {
    const int cur = tile & 1;
    if (tile + 1 < 16) {
      const int nxt = cur ^ 1;
      const size_t kofs = (size_t)(tile + 1) * 64;
      gload16(Kg + (kofs + r0) * 128 + sb0 * 16, (char*)Ks[nxt] + g0 * 16);
      gload16(Kg + (kofs + r1) * 128 + sb1 * 16, (char*)Ks[nxt] + g1 * 16);
      gload16(Vg + (size_t)r0 * 2048 + kofs * 2 + sb0 * 16, (char*)Vs[nxt] + g0 * 16);
      gload16(Vg + (size_t)r1 * 2048 + kofs * 2 + sb1 * 16, (char*)Vs[nxt] + g1 * 16);
      WAIT_VM4();   // oldest 4 (current tile) landed; next tile stays in flight
    } else {
      WAIT_VM0();
    }
    S_BARRIER();    // current tile visible to all waves

    const __bf16* Kc = Ks[cur];
    const __bf16* Vc = Vs[cur];

    // ---- S = Q @ K^T : 32 q-rows x 64 keys ----
    f32x4 s[2][4];
    #pragma unroll
    for (int m = 0; m < 2; ++m)
      #pragma unroll
      for (int ct = 0; ct < 4; ++ct) s[m][ct] = { 0.f, 0.f, 0.f, 0.f };
    __builtin_amdgcn_s_setprio(1);
    #pragma unroll
    for (int ct = 0; ct < 4; ++ct) {
      #pragma unroll
      for (int ks = 0; ks < 2; ++ks) {
        const int row = ct * 16 + rl;
        const int blk = (ks * 4 + gs) ^ (row & 7);
        bf16x8 kf = *(const bf16x8*)(Kc + row * 64 + blk * 8);
        s[0][ct] = __builtin_amdgcn_mfma_f32_16x16x32_bf16(aq[0][ks], kf, s[0][ct], 0, 0, 0);
        s[1][ct] = __builtin_amdgcn_mfma_f32_16x16x32_bf16(aq[1][ks], kf, s[1][ct], 0, 0, 0);
      }
    }
    __builtin_amdgcn_s_setprio(0);

    // ---- P = exp2(S'), local denom accumulate; no max, no rescale, no shuffles ----
    #pragma unroll
    for (int m = 0; m < 2; ++m) {
      #pragma unroll
      for (int b = 0; b < 4; ++b) {
        float rs = 0.f;
        #pragma unroll
        for (int ct = 0; ct < 4; ++ct) {
          const float p = exp2_fast(s[m][ct][b]);
          rs += p;
          Pw[(m * 16 + gs * 4 + b) * 72 + ct * 16 + rl] = (__bf16)p;
        }
        L[m][b] += rs;
      }
    }

    WAIT_LGKM();    // all 64 lanes' P writes visible before cross-lane reads
    bf16x8 ap[2][2];
    #pragma unroll
    for (int m = 0; m < 2; ++m)
      #pragma unroll
      for (int ks = 0; ks < 2; ++ks)
        ap[m][ks] = *(const bf16x8*)(Pw + (m * 16 + rl) * 72 + ks * 32 + gs * 8);

    // ---- O += P @ V ----
    __builtin_amdgcn_s_setprio(1);
    #pragma unroll
    for (int dt = 0; dt < 4; ++dt) {
      #pragma unroll
      for (int ks = 0; ks < 2; ++ks) {
        const int row = dt * 16 + rl;
        const int blk = (ks * 4 + gs) ^ (row & 7);
        bf16x8 vf = *(const bf16x8*)(Vc + row * 64 + blk * 8);
        accO[0][dt] = __builtin_amdgcn_mfma_f32_16x16x32_bf16(ap[0][ks], vf, accO[0][dt], 0, 0, 0);
        accO[1][dt] = __builtin_amdgcn_mfma_f32_16x16x32_bf16(ap[1][ks], vf, accO[1][dt], 0, 0, 0);
      }
    }
    __builtin_amdgcn_s_setprio(0);

    S_BARRIER();    // all waves done reading tile before it is overwritten
  }

  // final denominator: reduce per-lane partial sums across the 16 rl-lanes (once)
  float invL[2][4];
  #pragma unroll
  for (int m = 0; m < 2; ++m)
    #pragma unroll
    for (int b = 0; b < 4; ++b) {
      float rs = L[m][b];
      #pragma unroll
      for (int off = 1; off < 16; off <<= 1) rs += __shfl_xor(rs, off, 16);
      invL[m][b] = 1.0f / rs;
    }

  const int batch = bh / 12, hh = bh - batch * 12;
  #pragma unroll
  for (int m = 0; m < 2; ++m) {
    const size_t rowbase = (size_t)batch * 1024 + qt * 128 + w * 32 + m * 16 + gs * 4;
    #pragma unroll
    for (int dt = 0; dt < 4; ++dt)
      #pragma unroll
      for (int b = 0; b < 4; ++b)
        Ob[(rowbase + b) * 768 + hh * 64 + dt * 16 + rl] = (__bf16)(accO[m][dt][b] * invL[m][b]);
  }
}

// ---------------- launch ----------------
extern "C" void kernel_launch(void* const* d_in, const int* in_sizes, int n_in,
                              void* d_out, int out_size, void* d_ws, size_t ws_size,
                              hipStream_t stream) {
  const float* x      = (const float*)d_in[0];
  const float* ln1_g  = (const float*)d_in[1];
  const float* ln1_b  = (const float*)d_in[2];
  const float* w_qkv  = (const float*)d_in[3];
  const float* w_proj = (const float*)d_in[4];
  const float* b_proj = (const float*)d_in[5];
  const float* ls1    = (const float*)d_in[6];
  const float* ln2_g  = (const float*)d_in[7];
  const float* ln2_b  = (const float*)d_in[8];
  const float* w_fc1  = (const float*)d_in[9];
  const float* b_fc1  = (const float*)d_in[10];
  const float* w_fc2  = (const float*)d_in[11];
  const float* b_fc2  = (const float*)d_in[12];
  const float* ls2    = (const float*)d_in[13];
  float* out = (float*)d_out;

  char* ws = (char*)d_ws;
  size_t off = 0;
  auto alloc = [&](size_t bytes) { char* p = ws + off; off += (bytes + 255) & ~(size_t)255; return p; };
  __bf16* h1    = (__bf16*)alloc(8192ull * 768 * 2);   // LN1 out; later reused as attn_out
  __bf16* wqkvb = (__bf16*)alloc(2304ull * 768 * 2);
  __bf16* wprjb = (__bf16*)alloc(768ull * 768 * 2);
  __bf16* wfc1b = (__bf16*)alloc(3072ull * 768 * 2);
  __bf16* wfc2b = (__bf16*)alloc(768ull * 3072 * 2);
  __bf16* Qb    = (__bf16*)alloc(8192ull * 768 * 2);   // later reused as h2
  __bf16* Kb    = (__bf16*)alloc(8192ull * 768 * 2);
  __bf16* Vt    = (__bf16*)alloc(8192ull * 768 * 2);
  float*  out1  = (float*)alloc(8192ull * 768 * 4);
  __bf16* fc1o  = (__bf16*)alloc(8192ull * 3072 * 2);

  ln_kernel<<<8192, 256, 0, stream>>>(x, ln1_g, ln1_b, h1);
  cast4_kernel<<<2048, 256, 0, stream>>>(w_qkv, w_proj, w_fc1, w_fc2,
                                         wqkvb, wprjb, wfc1b, wfc2b);

  gemm_kernel<0, 128, 64, 64><<<dim3(36, 64), 256, 0, stream>>>(h1, wqkvb, 768,
      nullptr, nullptr, nullptr, nullptr, nullptr, Qb, Kb, Vt);

  attn_kernel<<<96 * 8, 256, 0, stream>>>(Qb, Kb, Vt, h1);  // h1 = attn_out now

  gemm_kernel<1, 128, 64, 64><<<dim3(12, 64), 256, 0, stream>>>(h1, wprjb, 768,
      b_proj, x, ls1, out1, nullptr, nullptr, nullptr, nullptr);

  ln_kernel<<<8192, 256, 0, stream>>>(out1, ln2_g, ln2_b, Qb);  // Qb = h2 now

  gemm_kernel<2, 128, 64, 64><<<dim3(48, 64), 256, 0, stream>>>(Qb, wfc1b, 768,
      b_fc1, nullptr, nullptr, nullptr, fc1o, nullptr, nullptr, nullptr);

  gemm_kernel<3, 128, 64, 64><<<dim3(12, 64), 256, 0, stream>>>(fc1o, wfc2b, 3072,
      b_fc2, out1, ls2, out, nullptr, nullptr, nullptr, nullptr);
}

// Round 11
// 182.844 us; speedup vs baseline: 1.6369x; 1.3716x over previous
//
#include <hip/hip_runtime.h>
#include <cstdint>
#include <cstddef>

typedef __bf16 bf16x8 __attribute__((ext_vector_type(8)));
typedef __bf16 bf16x4 __attribute__((ext_vector_type(4)));
typedef float f32x4 __attribute__((ext_vector_type(4)));
typedef int i32x4 __attribute__((ext_vector_type(4)));
typedef int i32x8 __attribute__((ext_vector_type(8)));

__device__ __forceinline__ void gload16(const void* g, void* l) {
  __builtin_amdgcn_global_load_lds((const __attribute__((address_space(1))) void*)g,
                                   (__attribute__((address_space(3))) void*)l, 16, 0, 0);
}

__device__ __forceinline__ float exp2_fast(float x) {
  float r;
  asm("v_exp_f32 %0, %1" : "=v"(r) : "v"(x));
  return r;
}
__device__ __forceinline__ float rcp_fast(float x) {
  float r;
  asm("v_rcp_f32 %0, %1" : "=v"(r) : "v"(x));
  return r;
}

// f32 -> OCP e4m3 (single value, low byte of packed cvt)
__device__ __forceinline__ unsigned char f32_to_fp8(float x) {
  int p = __builtin_amdgcn_cvt_pk_fp8_f32(x, 0.f, 0, false);
  return (unsigned char)(p & 0xff);
}
// f32x4 -> 4 packed e4m3 bytes
__device__ __forceinline__ unsigned int f32x4_to_fp8x4(float a, float b, float c, float d) {
  int p0 = __builtin_amdgcn_cvt_pk_fp8_f32(a, b, 0, false);
  int p1 = __builtin_amdgcn_cvt_pk_fp8_f32(c, d, 0, false);
  return (unsigned int)((p0 & 0xffff) | ((p1 & 0xffff) << 16));
}

template<int N> __device__ __forceinline__ void wait_vm() {
  if constexpr (N == 0) asm volatile("s_waitcnt vmcnt(0)" ::: "memory");
  else if constexpr (N == 4) asm volatile("s_waitcnt vmcnt(4)" ::: "memory");
  else if constexpr (N == 6) asm volatile("s_waitcnt vmcnt(6)" ::: "memory");
}

#define S_BARRIER() __builtin_amdgcn_s_barrier()
#define WAIT_VM4()  asm volatile("s_waitcnt vmcnt(4)" ::: "memory")
#define WAIT_VM0()  asm volatile("s_waitcnt vmcnt(0)" ::: "memory")
#define WAIT_LGKM() asm volatile("s_waitcnt lgkmcnt(0)" ::: "memory")

// ---------------- LayerNorm: fp32 in -> fp8 out (row = 768) ----------------
__global__ __launch_bounds__(256) void ln_kernel(const float* __restrict__ x,
    const float* __restrict__ g, const float* __restrict__ b,
    unsigned char* __restrict__ out)
{
  __shared__ float red[8];
  const int row = blockIdx.x, t = threadIdx.x;
  const float* xr = x + (size_t)row * 768;
  float v0 = xr[t], v1 = xr[t + 256], v2 = xr[t + 512];
  float s = v0 + v1 + v2;
  float q = v0 * v0 + v1 * v1 + v2 * v2;
  #pragma unroll
  for (int off = 32; off > 0; off >>= 1) {
    s += __shfl_xor(s, off, 64);
    q += __shfl_xor(q, off, 64);
  }
  const int w = t >> 6;
  if ((t & 63) == 0) { red[w] = s; red[4 + w] = q; }
  __syncthreads();
  s = red[0] + red[1] + red[2] + red[3];
  q = red[4] + red[5] + red[6] + red[7];
  const float mu = s * (1.0f / 768.0f);
  const float var = q * (1.0f / 768.0f) - mu * mu;
  const float rstd = rsqrtf(var + 1e-5f);
  unsigned char* orow = out + (size_t)row * 768;
  orow[t]       = f32_to_fp8((v0 - mu) * rstd * g[t]       + b[t]);
  orow[t + 256] = f32_to_fp8((v1 - mu) * rstd * g[t + 256] + b[t + 256]);
  orow[t + 512] = f32_to_fp8((v2 - mu) * rstd * g[t + 512] + b[t + 512]);
}

// ---------------- fused fp32 -> fp8 cast of all 4 weight matrices ----------------
__global__ __launch_bounds__(256) void cast4_kernel(
    const float* __restrict__ i0, const float* __restrict__ i1,
    const float* __restrict__ i2, const float* __restrict__ i3,
    unsigned char* __restrict__ o0, unsigned char* __restrict__ o1,
    unsigned char* __restrict__ o2, unsigned char* __restrict__ o3)
{
  const int n0 = 2304 * 768 / 4, n1 = 768 * 768 / 4;
  const int n2 = 3072 * 768 / 4, n3 = 768 * 3072 / 4;
  const int total = n0 + n1 + n2 + n3;
  for (int i = blockIdx.x * 256 + threadIdx.x; i < total; i += gridDim.x * 256) {
    const float* in; unsigned char* out; int j = i;
    if (j < n0) { in = i0; out = o0; }
    else if ((j -= n0) < n1) { in = i1; out = o1; }
    else if ((j -= n1) < n2) { in = i2; out = o2; }
    else { j -= n2; in = i3; out = o3; }
    float4 v = ((const float4*)in)[j];
    ((unsigned int*)out)[j] = f32x4_to_fp8x4(v.x, v.y, v.z, v.w);
  }
}

// ---------------- GEMM v9 (MX-FP8): C = A[M,K](e4m3) @ W[N,K]^T(e4m3) ----------------
// 128x64 tile, BK=128 fp8, 4 waves (2x2), mfma_scale_f32_16x16x128_f8f6f4 (scales=1.0).
// NBUF=2, depth-1 counted prefetch, vmcnt(6), 48 KB LDS (3 blocks/CU).
// nk = K/128 (6 for K=768): barrier-pairs per FLOP halved vs bf16 BK=64.
// 16B-granule XOR swizzle gc^=row&7 (both-sides) -> rows 0-7 conflict-free, 2-way on 8-row alias (free).
// XCD-aware bijective block swizzle.
// MODE 0: QKV scatter -> bf16 (Q scaled 0.125*log2e, V transposed).
// MODE 1: proj (+bias, resid+ls -> f32). MODE 2: fc1 (+bias, fast GELU -> fp8).
// MODE 3: fc2 (+bias, resid+ls -> f32).
template<int MODE>
__global__ __launch_bounds__(256) void gemm_kernel(
    const unsigned char* __restrict__ A, const unsigned char* __restrict__ W, int K,
    const float* __restrict__ bias, const float* __restrict__ resid,
    const float* __restrict__ ls, float* __restrict__ outf,
    unsigned char* __restrict__ outb,
    __bf16* __restrict__ qo, __bf16* __restrict__ ko, __bf16* __restrict__ vo)
{
  constexpr int BM = 128, BN = 64, BK = 128;
  constexpr int FM = 4, FN = 2;
  __shared__ unsigned char As[2 * BM * BK];   // 2 x 16 KB
  __shared__ unsigned char Bs[2 * BN * BK];   // 2 x 8 KB

  // XCD-aware swizzle of the linear block id (bijective: nwg % 8 == 0)
  const int nx = gridDim.x;
  const int nwg = nx * gridDim.y;
  const int orig = blockIdx.x + nx * blockIdx.y;
  const int nid = (orig & 7) * (nwg >> 3) + (orig >> 3);
  const int bx = nid % nx, by = nid / nx;

  const int t = threadIdx.x;
  const int lane = t & 63;
  const int w = t >> 6;
  const int wm = w >> 1, wn = w & 1;
  const int m0 = by * BM, n0 = bx * BN;
  const int rl = lane & 15, gs = lane >> 4;

  f32x4 acc[FM][FN];
  #pragma unroll
  for (int i = 0; i < FM; ++i)
    #pragma unroll
    for (int j = 0; j < FN; ++j) acc[i][j] = { 0.f, 0.f, 0.f, 0.f };

  // staging sources: 16B granules, 8 per 128B row; physical granule gc holds
  // logical granule gc^(row&7)  (pre-swizzled global source, linear LDS dest)
  const unsigned char* Asrc[4];
  const unsigned char* Bsrc[2];
  #pragma unroll
  for (int i = 0; i < 4; ++i) {
    const int g = i * 256 + t, row = g >> 3, gc = g & 7;
    Asrc[i] = A + (size_t)(m0 + row) * K + ((gc ^ (row & 7)) << 4);
  }
  #pragma unroll
  for (int i = 0; i < 2; ++i) {
    const int g = i * 256 + t, row = g >> 3, gc = g & 7;
    Bsrc[i] = W + (size_t)(n0 + row) * K + ((gc ^ (row & 7)) << 4);
  }

  auto stage = [&](int kt, int buf) {
    const int k0 = kt << 7;
    #pragma unroll
    for (int i = 0; i < 4; ++i)
      gload16(Asrc[i] + k0, As + buf * 16384 + (i * 256 + t) * 16);
    #pragma unroll
    for (int i = 0; i < 2; ++i)
      gload16(Bsrc[i] + k0, Bs + buf * 8192 + (i * 256 + t) * 16);
  };

  // fragment load: 32 logical-contiguous fp8 (k = gs*32..gs*32+31) via 2 swizzled b128 reads
  auto ld32 = [&](const unsigned char* rowbase, int sw) -> i32x8 {
    const i32x4 lo = *(const i32x4*)(rowbase + (((2 * gs + 0) ^ sw) << 4));
    const i32x4 hi = *(const i32x4*)(rowbase + (((2 * gs + 1) ^ sw) << 4));
    i32x8 r;
    r[0] = lo[0]; r[1] = lo[1]; r[2] = lo[2]; r[3] = lo[3];
    r[4] = hi[0]; r[5] = hi[1]; r[6] = hi[2]; r[7] = hi[3];
    return r;
  };

  const int nk = K >> 7;          // 6 (K=768) or 24 (K=3072)
  stage(0, 0);

  #pragma unroll 2
  for (int kt = 0; kt < nk; ++kt) {
    const int cur = kt & 1;
    if (kt + 1 < nk) { stage(kt + 1, cur ^ 1); wait_vm<6>(); }
    else             { wait_vm<0>(); }
    S_BARRIER();                  // tile kt resident for all waves

    const unsigned char* Ac = As + cur * 16384;
    const unsigned char* Bc = Bs + cur * 8192;
    i32x8 af[FM], bfr[FN];
    #pragma unroll
    for (int fm = 0; fm < FM; ++fm) {
      const int row = wm * 64 + fm * 16 + rl;
      af[fm] = ld32(Ac + row * 128, row & 7);
    }
    #pragma unroll
    for (int fn = 0; fn < FN; ++fn) {
      const int row = wn * 32 + fn * 16 + rl;
      bfr[fn] = ld32(Bc + row * 128, row & 7);
    }
    #pragma unroll
    for (int fm = 0; fm < FM; ++fm)
      #pragma unroll
      for (int fn = 0; fn < FN; ++fn)
        acc[fm][fn] = __builtin_amdgcn_mfma_scale_f32_16x16x128_f8f6f4(
            af[fm], bfr[fn], acc[fm][fn],
            0, 0,                       // cbsz: A=fp8, blgp: B=fp8
            0, 0x7F7F7F7F,              // scale A opsel, e8m0 1.0
            0, 0x7F7F7F7F);             // scale B opsel, e8m0 1.0

    S_BARRIER();                  // all waves done with tile kt before re-staging
  }

  // epilogue: C row = m0+wm*64+fm*16+gs*4+b ; col = n0+wn*32+fn*16+rl
  #pragma unroll
  for (int fm = 0; fm < FM; ++fm) {
    const int rbase = m0 + wm * 64 + fm * 16 + gs * 4;
    #pragma unroll
    for (int fn = 0; fn < FN; ++fn) {
      const int c = n0 + wn * 32 + fn * 16 + rl;
      #pragma unroll
      for (int b = 0; b < 4; ++b) {
        const int r = rbase + b;
        const float val = acc[fm][fn][b];
        if constexpr (MODE == 0) {
          const int sec = c / 768;
          const int cc = c - sec * 768;
          const int hh = cc >> 6, d = cc & 63;
          const int batch = r >> 10, n = r & 1023;
          const size_t bh = (size_t)(batch * 12 + hh);
          // Q scaled by (1/8)*log2(e) so softmax uses raw v_exp_f32 (2^x)
          if (sec == 0)      qo[(bh * 1024 + n) * 64 + d] = (__bf16)(val * 0.1803368801111204f);
          else if (sec == 1) ko[(bh * 1024 + n) * 64 + d] = (__bf16)val;
          else               vo[(bh * 64 + d) * 1024 + n] = (__bf16)val;
        } else if constexpr (MODE == 1) {
          const size_t idx = (size_t)r * 768 + c;
          outf[idx] = resid[idx] + ls[c] * (val + bias[c]);
        } else if constexpr (MODE == 2) {
          // fast GELU: h*sigmoid(2*0.7978845608*(h+0.044715 h^3)), exp2-folded.
          const float h = val + bias[c];
          const float z = h * (1.0f + 0.044715f * h * h);
          const float e = exp2_fast(2.3021181f * z);
          const float gl = h - h * rcp_fast(1.0f + e);
          outb[(size_t)r * 3072 + c] = f32_to_fp8(gl);
        } else {
          const size_t idx = (size_t)r * 768 + c;
          outf[idx] = resid[idx] + ls[c] * (val + bias[c]);
        }
      }
    }
  }
}

// ---------------- Flash attention (fixed-max exp2 softmax, deferred denom) ----
// Q: [96][1024][64] bf16 pre-scaled by 0.125*log2e. K: [96][1024][64]. Vt: [96][64][1024].
// Output now fp8 (proj's A input). Head-locality XCD mapping (bh%8 == nid%8).
__global__ __launch_bounds__(256, 3) void attn_kernel(
    const __bf16* __restrict__ Q, const __bf16* __restrict__ Kb,
    const __bf16* __restrict__ Vt, unsigned char* __restrict__ Ob)
{
  __shared__ __bf16 Ks[2][64 * 64];     // 2 x 8 KB
  __shared__ __bf16 Vs[2][64 * 64];     // 2 x 8 KB
  __shared__ __bf16 P_lds[4][32 * 72];  // per-wave P, rows padded to 72 halves (18 KB)

  const int nid = blockIdx.x;
  const int b7 = nid & 7, rest = nid >> 3;
  const int qt = rest & 7;
  const int bh = b7 + ((rest >> 3) << 3);

  const int t = threadIdx.x, lane = t & 63, w = t >> 6;
  const int rl = lane & 15, gs = lane >> 4;
  const int q0 = qt * 128 + w * 32;
  const __bf16* Qh = Q  + (size_t)bh * 1024 * 64;
  const char*   Kg = (const char*)(Kb + (size_t)bh * 1024 * 64);
  const char*   Vg = (const char*)(Vt + (size_t)bh * 64 * 1024);
  __bf16* Pw = &P_lds[w][0];

  const int g0 = w * 64 + lane;         // 0..255
  const int g1 = 256 + g0;              // 256..511
  const int r0 = g0 >> 3, sb0 = (g0 & 7) ^ (r0 & 7);
  const int r1 = g1 >> 3, sb1 = (g1 & 7) ^ (r1 & 7);

  bf16x8 aq[2][2];
  #pragma unroll
  for (int m = 0; m < 2; ++m)
    #pragma unroll
    for (int ks = 0; ks < 2; ++ks)
      aq[m][ks] = *(const bf16x8*)(Qh + (size_t)(q0 + m * 16 + rl) * 64 + ks * 32 + gs * 8);

  f32x4 accO[2][4];
  #pragma unroll
  for (int m = 0; m < 2; ++m)
    #pragma unroll
    for (int d = 0; d < 4; ++d) accO[m][d] = { 0.f, 0.f, 0.f, 0.f };
  float L[2][4];
  #pragma unroll
  for (int m = 0; m < 2; ++m)
    #pragma unroll
    for (int b = 0; b < 4; ++b) L[m][b] = 0.f;

  {
    gload16(Kg + (size_t)r0 * 128 + sb0 * 16, (char*)Ks[0] + g0 * 16);
    gload16(Kg + (size_t)r1 * 128 + sb1 * 16, (char*)Ks[0] + g1 * 16);
    gload16(Vg + (size_t)r0 * 2048 + sb0 * 16, (char*)Vs[0] + g0 * 16);
    gload16(Vg + (size_t)r1 * 2048 + sb1 * 16, (char*)Vs[0] + g1 * 16);
  }

  for (int tile = 0; tile < 16; ++tile) {
    const int cur = tile & 1;
    if (tile + 1 < 16) {
      const int nxt = cur ^ 1;
      const size_t kofs = (size_t)(tile + 1) * 64;
      gload16(Kg + (kofs + r0) * 128 + sb0 * 16, (char*)Ks[nxt] + g0 * 16);
      gload16(Kg + (kofs + r1) * 128 + sb1 * 16, (char*)Ks[nxt] + g1 * 16);
      gload16(Vg + (size_t)r0 * 2048 + kofs * 2 + sb0 * 16, (char*)Vs[nxt] + g0 * 16);
      gload16(Vg + (size_t)r1 * 2048 + kofs * 2 + sb1 * 16, (char*)Vs[nxt] + g1 * 16);
      WAIT_VM4();
    } else {
      WAIT_VM0();
    }
    S_BARRIER();

    const __bf16* Kc = Ks[cur];
    const __bf16* Vc = Vs[cur];

    f32x4 s[2][4];
    #pragma unroll
    for (int m = 0; m < 2; ++m)
      #pragma unroll
      for (int ct = 0; ct < 4; ++ct) s[m][ct] = { 0.f, 0.f, 0.f, 0.f };
    __builtin_amdgcn_s_setprio(1);
    #pragma unroll
    for (int ct = 0; ct < 4; ++ct) {
      #pragma unroll
      for (int ks = 0; ks < 2; ++ks) {
        const int row = ct * 16 + rl;
        const int blk = (ks * 4 + gs) ^ (row & 7);
        bf16x8 kf = *(const bf16x8*)(Kc + row * 64 + blk * 8);
        s[0][ct] = __builtin_amdgcn_mfma_f32_16x16x32_bf16(aq[0][ks], kf, s[0][ct], 0, 0, 0);
        s[1][ct] = __builtin_amdgcn_mfma_f32_16x16x32_bf16(aq[1][ks], kf, s[1][ct], 0, 0, 0);
      }
    }
    __builtin_amdgcn_s_setprio(0);

    #pragma unroll
    for (int m = 0; m < 2; ++m) {
      #pragma unroll
      for (int b = 0; b < 4; ++b) {
        float rs = 0.f;
        #pragma unroll
        for (int ct = 0; ct < 4; ++ct) {
          const float p = exp2_fast(s[m][ct][b]);
          rs += p;
          Pw[(m * 16 + gs * 4 + b) * 72 + ct * 16 + rl] = (__bf16)p;
        }
        L[m][b] += rs;
      }
    }

    WAIT_LGKM();
    bf16x8 ap[2][2];
    #pragma unroll
    for (int m = 0; m < 2; ++m)
      #pragma unroll
      for (int ks = 0; ks < 2; ++ks)
        ap[m][ks] = *(const bf16x8*)(Pw + (m * 16 + rl) * 72 + ks * 32 + gs * 8);

    __builtin_amdgcn_s_setprio(1);
    #pragma unroll
    for (int dt = 0; dt < 4; ++dt) {
      #pragma unroll
      for (int ks = 0; ks < 2; ++ks) {
        const int row = dt * 16 + rl;
        const int blk = (ks * 4 + gs) ^ (row & 7);
        bf16x8 vf = *(const bf16x8*)(Vc + row * 64 + blk * 8);
        accO[0][dt] = __builtin_amdgcn_mfma_f32_16x16x32_bf16(ap[0][ks], vf, accO[0][dt], 0, 0, 0);
        accO[1][dt] = __builtin_amdgcn_mfma_f32_16x16x32_bf16(ap[1][ks], vf, accO[1][dt], 0, 0, 0);
      }
    }
    __builtin_amdgcn_s_setprio(0);

    S_BARRIER();
  }

  float invL[2][4];
  #pragma unroll
  for (int m = 0; m < 2; ++m)
    #pragma unroll
    for (int b = 0; b < 4; ++b) {
      float rs = L[m][b];
      #pragma unroll
      for (int off = 1; off < 16; off <<= 1) rs += __shfl_xor(rs, off, 16);
      invL[m][b] = 1.0f / rs;
    }

  const int batch = bh / 12, hh = bh - batch * 12;
  #pragma unroll
  for (int m = 0; m < 2; ++m) {
    const size_t rowbase = (size_t)batch * 1024 + qt * 128 + w * 32 + m * 16 + gs * 4;
    #pragma unroll
    for (int dt = 0; dt < 4; ++dt)
      #pragma unroll
      for (int b = 0; b < 4; ++b)
        Ob[(rowbase + b) * 768 + hh * 64 + dt * 16 + rl] = f32_to_fp8(accO[m][dt][b] * invL[m][b]);
  }
}

// ---------------- launch ----------------
extern "C" void kernel_launch(void* const* d_in, const int* in_sizes, int n_in,
                              void* d_out, int out_size, void* d_ws, size_t ws_size,
                              hipStream_t stream) {
  const float* x      = (const float*)d_in[0];
  const float* ln1_g  = (const float*)d_in[1];
  const float* ln1_b  = (const float*)d_in[2];
  const float* w_qkv  = (const float*)d_in[3];
  const float* w_proj = (const float*)d_in[4];
  const float* b_proj = (const float*)d_in[5];
  const float* ls1    = (const float*)d_in[6];
  const float* ln2_g  = (const float*)d_in[7];
  const float* ln2_b  = (const float*)d_in[8];
  const float* w_fc1  = (const float*)d_in[9];
  const float* b_fc1  = (const float*)d_in[10];
  const float* w_fc2  = (const float*)d_in[11];
  const float* b_fc2  = (const float*)d_in[12];
  const float* ls2    = (const float*)d_in[13];
  float* out = (float*)d_out;

  char* ws = (char*)d_ws;
  size_t off = 0;
  auto alloc = [&](size_t bytes) { char* p = ws + off; off += (bytes + 255) & ~(size_t)255; return p; };
  unsigned char* h1    = (unsigned char*)alloc(8192ull * 768);      // LN1 out (fp8); later attn_out (fp8)
  unsigned char* wqkv8 = (unsigned char*)alloc(2304ull * 768);
  unsigned char* wprj8 = (unsigned char*)alloc(768ull * 768);
  unsigned char* wfc18 = (unsigned char*)alloc(3072ull * 768);
  unsigned char* wfc28 = (unsigned char*)alloc(768ull * 3072);
  __bf16* Qb    = (__bf16*)alloc(8192ull * 768 * 2);
  __bf16* Kb    = (__bf16*)alloc(8192ull * 768 * 2);
  __bf16* Vt    = (__bf16*)alloc(8192ull * 768 * 2);
  float*  out1  = (float*)alloc(8192ull * 768 * 4);
  unsigned char* fc1o = (unsigned char*)alloc(8192ull * 3072);
  unsigned char* h2   = (unsigned char*)alloc(8192ull * 768);       // LN2 out (fp8)

  ln_kernel<<<8192, 256, 0, stream>>>(x, ln1_g, ln1_b, h1);
  cast4_kernel<<<2048, 256, 0, stream>>>(w_qkv, w_proj, w_fc1, w_fc2,
                                         wqkv8, wprj8, wfc18, wfc28);

  gemm_kernel<0><<<dim3(36, 64), 256, 0, stream>>>(h1, wqkv8, 768,
      nullptr, nullptr, nullptr, nullptr, nullptr, Qb, Kb, Vt);

  attn_kernel<<<96 * 8, 256, 0, stream>>>(Qb, Kb, Vt, h1);  // h1 = attn_out (fp8) now

  gemm_kernel<1><<<dim3(12, 64), 256, 0, stream>>>(h1, wprj8, 768,
      b_proj, x, ls1, out1, nullptr, nullptr, nullptr, nullptr);

  ln_kernel<<<8192, 256, 0, stream>>>(out1, ln2_g, ln2_b, h2);

  gemm_kernel<2><<<dim3(48, 64), 256, 0, stream>>>(h2, wfc18, 768,
      b_fc1, nullptr, nullptr, nullptr, fc1o, nullptr, nullptr, nullptr);

  gemm_kernel<3><<<dim3(12, 64), 256, 0, stream>>>(fc1o, wfc28, 3072,
      b_fc2, out1, ls2, out, nullptr, nullptr, nullptr, nullptr);
}